// Round 4
// baseline (662.810 us; speedup 1.0000x reference)
//
#include <hip/hip_runtime.h>
#include <stdint.h>

// L=S=1024, N=16, E=1024, single head.
// Inputs/output: FLOAT32. Internal compute: bf16 MFMA.
// d_ws footprint: EXACTLY 64 MB (never assume more):
//   W0 [0,32MB)  = Vt[n][f][s] bf16
//   W1 [32,64MB) = Vproj temp -> scores -> attn (bf16)
// Q/K bf16 staging lives in d_out (dead before final PV overwrites it).

#define BM 128
#define BN 128
#define BK 32

typedef __attribute__((ext_vector_type(8))) short bf16x8;   // 8 bf16 = 4 VGPRs
typedef __attribute__((ext_vector_type(4))) float f32x4;    // MFMA 16x16 accum

__device__ __forceinline__ float bf2f(unsigned short u) {
    union { unsigned int i; float f; } w; w.i = ((unsigned int)u) << 16; return w.f;
}
__device__ __forceinline__ unsigned short f2bf(float f) {
    union { float f; unsigned int i; } w; w.f = f;
    unsigned int r = (w.i + 0x7FFFu + ((w.i >> 16) & 1u)) >> 16;  // RNE
    return (unsigned short)r;
}

// async global->LDS, 16B/lane; LDS dest is wave-uniform base + lane*16B
__device__ __forceinline__ void g2l16(const unsigned short* g, unsigned short* l) {
    __builtin_amdgcn_global_load_lds(
        (const __attribute__((address_space(1))) unsigned int*)g,
        (__attribute__((address_space(3))) unsigned int*)l, 16, 0, 0);
}

// Stage one 16-row group of a BK=32 tile into LDS (bf16).
//  - bf16 source: async global_load_lds (wave-uniform dest base).
//  - f32 source: load 8 floats/lane, RNE-convert, ds_write 16B to same slot.
template <typename T>
__device__ __forceinline__ void stage16(const T* __restrict__ gRow,
                                        unsigned short* lbase, int lane) {
    if constexpr (sizeof(T) == 2) {
        g2l16((const unsigned short*)gRow, lbase);
    } else {
        const float4* gp = (const float4*)gRow;
        float4 a = gp[0], b = gp[1];
        bf16x8 v;
        v[0] = (short)f2bf(a.x); v[1] = (short)f2bf(a.y);
        v[2] = (short)f2bf(a.z); v[3] = (short)f2bf(a.w);
        v[4] = (short)f2bf(b.x); v[5] = (short)f2bf(b.y);
        v[6] = (short)f2bf(b.z); v[7] = (short)f2bf(b.w);
        *(bf16x8*)(lbase + lane * 8) = v;
    }
}

// C[m][n] = (sum_k A[m][k]*B[n][k] + bias[n]) * scale   (BT-GEMM, m97 pattern)
template <typename AT, typename BT, typename OutT, bool HAS_BIAS>
__global__ __launch_bounds__(256) void gemm_bt(
    const AT* __restrict__ A,
    const BT* __restrict__ B,
    OutT* __restrict__ C,
    const float* __restrict__ bias,
    float scale, int K,
    long lda, long ldb, long ldc,
    long aBatch, long bBatch, long cBatch)
{
    __shared__ __align__(16) unsigned short As[BM * BK];
    __shared__ __align__(16) unsigned short Bs[BN * BK];

    const int tid  = threadIdx.x;
    const int wave = tid >> 6;
    const int lane = tid & 63;
    const int lr   = lane & 15;
    const int q4   = lane >> 4;
    const int wm   = wave >> 1;
    const int wn   = wave & 1;

    const long m0 = (long)blockIdx.y * BM;
    const long n0 = (long)blockIdx.x * BN;
    A += (long)blockIdx.z * aBatch;
    B += (long)blockIdx.z * bBatch;
    C += (long)blockIdx.z * cBatch;

    const int srow  = lane >> 2;       // staging row within 16-row group
    const int skoff = (lane & 3) * 8;  // staging element offset in K

    f32x4 acc[4][4];
    const f32x4 zero = {0.f, 0.f, 0.f, 0.f};
#pragma unroll
    for (int i = 0; i < 4; i++)
#pragma unroll
        for (int j = 0; j < 4; j++) acc[i][j] = zero;

    const int nkt = K / BK;
    for (int kt = 0; kt < nkt; kt++) {
        const long k0 = (long)kt * BK;
        __syncthreads();
#pragma unroll
        for (int iss = 0; iss < 2; iss++) {
            const int rbase = wave * 32 + iss * 16;   // wave-uniform
            stage16(A + (m0 + rbase + srow) * lda + k0 + skoff, &As[rbase * BK], lane);
            stage16(B + (n0 + rbase + srow) * ldb + k0 + skoff, &Bs[rbase * BK], lane);
        }
        __syncthreads();

        bf16x8 af[4], bfr[4];
#pragma unroll
        for (int mi = 0; mi < 4; mi++)
            af[mi] = *(const bf16x8*)&As[(wm * 64 + mi * 16 + lr) * BK + q4 * 8];
#pragma unroll
        for (int ni = 0; ni < 4; ni++)
            bfr[ni] = *(const bf16x8*)&Bs[(wn * 64 + ni * 16 + lr) * BK + q4 * 8];
#pragma unroll
        for (int mi = 0; mi < 4; mi++)
#pragma unroll
            for (int ni = 0; ni < 4; ni++)
                acc[mi][ni] = __builtin_amdgcn_mfma_f32_16x16x32_bf16(
                    af[mi], bfr[ni], acc[mi][ni], 0, 0, 0);
    }

    // Verified C/D mapping: col = lane&15, row = quad*4 + reg.
#pragma unroll
    for (int ni = 0; ni < 4; ni++) {
        const long col = n0 + wn * 64 + ni * 16 + lr;
        const float bv = HAS_BIAS ? bias[col] : 0.f;
#pragma unroll
        for (int mi = 0; mi < 4; mi++) {
            const long row = m0 + wm * 64 + mi * 16 + q4 * 4;
#pragma unroll
            for (int r = 0; r < 4; r++) {
                float v = (acc[mi][ni][r] + bv) * scale;
                if constexpr (sizeof(OutT) == 2)
                    C[(row + r) * ldc + col] = (OutT)f2bf(v);
                else
                    C[(row + r) * ldc + col] = v;
            }
        }
    }
}

// Vproj[(s*16+n)*1024+f] bf16 -> Vt[n][f][s] bf16
__global__ __launch_bounds__(256) void transpose_v(
    const unsigned short* __restrict__ V, unsigned short* __restrict__ Vt)
{
    __shared__ unsigned short t[32][33];
    const int n = blockIdx.z;
    const int f0 = blockIdx.x * 32, s0 = blockIdx.y * 32;
    const int x = threadIdx.x;  // 0..31
#pragma unroll
    for (int i = threadIdx.y; i < 32; i += 8)
        t[i][x] = V[((long)(s0 + i) * 16 + n) * 1024 + f0 + x];
    __syncthreads();
#pragma unroll
    for (int i = threadIdx.y; i < 32; i += 8)
        Vt[(long)n * 1048576 + (long)(f0 + i) * 1024 + s0 + x] = t[x][i];
}

// In-place softmax on rows of 1024 bf16; f32 math; clamp keeps failures finite.
__global__ __launch_bounds__(256) void softmax_rows(unsigned short* __restrict__ base)
{
    unsigned short* p = base + (long)blockIdx.x * 1024;
    const int tid = threadIdx.x;
    ushort4 u = ((const ushort4*)p)[tid];
    float x0 = bf2f(u.x), x1 = bf2f(u.y), x2 = bf2f(u.z), x3 = bf2f(u.w);
    x0 = fminf(fmaxf(x0, -1e30f), 1e30f);
    x1 = fminf(fmaxf(x1, -1e30f), 1e30f);
    x2 = fminf(fmaxf(x2, -1e30f), 1e30f);
    x3 = fminf(fmaxf(x3, -1e30f), 1e30f);

    float m = fmaxf(fmaxf(x0, x1), fmaxf(x2, x3));
#pragma unroll
    for (int o = 32; o > 0; o >>= 1) m = fmaxf(m, __shfl_xor(m, o));
    __shared__ float redm[4], reds[4];
    const int wave = tid >> 6, lane = tid & 63;
    if (lane == 0) redm[wave] = m;
    __syncthreads();
    m = fmaxf(fmaxf(redm[0], redm[1]), fmaxf(redm[2], redm[3]));

    float e0 = __expf(x0 - m), e1 = __expf(x1 - m);
    float e2 = __expf(x2 - m), e3 = __expf(x3 - m);
    float s = e0 + e1 + e2 + e3;
#pragma unroll
    for (int o = 32; o > 0; o >>= 1) s += __shfl_xor(s, o);
    if (lane == 0) reds[wave] = s;
    __syncthreads();
    s = reds[0] + reds[1] + reds[2] + reds[3];
    const float inv = 1.0f / s;

    ushort4 ov = make_ushort4(f2bf(e0 * inv), f2bf(e1 * inv),
                              f2bf(e2 * inv), f2bf(e3 * inv));
    ((ushort4*)p)[tid] = ov;
}

extern "C" void kernel_launch(void* const* d_in, const int* in_sizes, int n_in,
                              void* d_out, int out_size, void* d_ws, size_t ws_size,
                              hipStream_t stream) {
    const float* query = (const float*)d_in[0];  // (1024,16,1024) f32
    const float* keyp  = (const float*)d_in[1];
    const float* valp  = (const float*)d_in[2];
    const float* wq    = (const float*)d_in[3];  // (1024,1024) f32
    const float* wk    = (const float*)d_in[4];
    const float* wv    = (const float*)d_in[5];
    const float* bias  = (const float*)d_in[6];  // (3072,) f32
    float* out = (float*)d_out;                  // 16777216 f32 = 64 MB

    // d_ws: exactly 64 MB used.
    unsigned short* W0 = (unsigned short*)d_ws;   // Vt[n][f][s], 32 MB
    unsigned short* W1 = W0 + 16777216;           // Vproj -> scores -> attn, 32 MB
    // Q/K bf16 staging inside d_out (dead before final PV write):
    unsigned short* Qb = (unsigned short*)d_out;  // bytes [0,32MB), rows l*16+n
    unsigned short* Kb = Qb + 16777216;           // bytes [32,64MB), rows s*16+n

    const dim3 blk(256, 1, 1);
    const float qscale = 0.03125f;  // E^-0.5

    // 1. V projection (f32) -> W1 bf16, row = s*16+n
    gemm_bt<float, float, unsigned short, true><<<dim3(8, 128, 1), blk, 0, stream>>>(
        valp, wv, W1, bias + 2048, 1.0f, 1024, 1024, 1024, 1024, 0, 0, 0);
    // 2. transpose -> W0 = Vt[n][f][s]; W1 now dead
    transpose_v<<<dim3(32, 32, 16), dim3(32, 8, 1), 0, stream>>>(W1, W0);
    // 3. Q projection -> Qb (d_out lower half), scaled by E^-0.5
    gemm_bt<float, float, unsigned short, true><<<dim3(8, 128, 1), blk, 0, stream>>>(
        query, wq, Qb, bias, qscale, 1024, 1024, 1024, 1024, 0, 0, 0);
    // 4. K projection -> Kb (d_out upper half)
    gemm_bt<float, float, unsigned short, true><<<dim3(8, 128, 1), blk, 0, stream>>>(
        keyp, wk, Kb, bias + 1024, 1.0f, 1024, 1024, 1024, 1024, 0, 0, 0);

    // 5. scores[n][l][s] bf16 -> W1 (overwrites dead Vproj)
    //    A row l at Qb + n*1024 + l*16384 ; B row s at Kb + n*1024 + s*16384
    gemm_bt<unsigned short, unsigned short, unsigned short, false>
        <<<dim3(8, 8, 16), blk, 0, stream>>>(
        Qb, Kb, W1, nullptr, 1.0f, 1024,
        16384, 16384, 1024, 1024, 1024, 1048576);

    // 6. softmax over s on all 16384 rows of W1 (in place)
    softmax_rows<<<dim3(16384, 1, 1), blk, 0, stream>>>(W1);

    // 7. out[(l*16+n)*1024+f] = attn_n[l][:] . Vt_n[f][:]
    //    Reads only W0/W1; overwrites ALL of d_out (Q/K staging dead).
    gemm_bt<unsigned short, unsigned short, float, false>
        <<<dim3(8, 8, 16), blk, 0, stream>>>(
        W1, W0, out, nullptr, 1.0f, 1024,
        1024, 1024, 16384, 1048576, 1048576, 1024);
}

// Round 5
// 644.932 us; speedup vs baseline: 1.0277x; 1.0277x over previous
//
#include <hip/hip_runtime.h>
#include <stdint.h>

// L=S=1024, N=16, E=1024, single head.
// Inputs/output: FLOAT32. Internal compute: bf16 MFMA.
// d_ws: exactly 64 MB (W0 = Vt, W1 = Vproj->scores->attn).
// Q/K bf16 staging lives in d_out (dead before final PV overwrites it).
//
// R4 change: 1-D grid + explicit (row,col,batch) decode with row in the low
// bits (gridM % 8 == 0), so the 8 column-blocks sharing an A-row-tile land on
// the SAME XCD (linear id % 8 picks the XCD). R3 counters showed 266 MB
// FETCH (4x ideal) from A-tiles being re-fetched by all 8 XCDs.

#define BM 128
#define BN 128
#define BK 32

typedef __attribute__((ext_vector_type(8))) short bf16x8;   // 8 bf16 = 4 VGPRs
typedef __attribute__((ext_vector_type(4))) float f32x4;    // MFMA 16x16 accum

__device__ __forceinline__ float bf2f(unsigned short u) {
    union { unsigned int i; float f; } w; w.i = ((unsigned int)u) << 16; return w.f;
}
__device__ __forceinline__ unsigned short f2bf(float f) {
    union { float f; unsigned int i; } w; w.f = f;
    unsigned int r = (w.i + 0x7FFFu + ((w.i >> 16) & 1u)) >> 16;  // RNE
    return (unsigned short)r;
}

// async global->LDS, 16B/lane; LDS dest is wave-uniform base + lane*16B
__device__ __forceinline__ void g2l16(const unsigned short* g, unsigned short* l) {
    __builtin_amdgcn_global_load_lds(
        (const __attribute__((address_space(1))) unsigned int*)g,
        (__attribute__((address_space(3))) unsigned int*)l, 16, 0, 0);
}

// Stage one 16-row group of a BK=32 tile into LDS (bf16).
template <typename T>
__device__ __forceinline__ void stage16(const T* __restrict__ gRow,
                                        unsigned short* lbase, int lane) {
    if constexpr (sizeof(T) == 2) {
        g2l16((const unsigned short*)gRow, lbase);
    } else {
        const float4* gp = (const float4*)gRow;
        float4 a = gp[0], b = gp[1];
        bf16x8 v;
        v[0] = (short)f2bf(a.x); v[1] = (short)f2bf(a.y);
        v[2] = (short)f2bf(a.z); v[3] = (short)f2bf(a.w);
        v[4] = (short)f2bf(b.x); v[5] = (short)f2bf(b.y);
        v[6] = (short)f2bf(b.z); v[7] = (short)f2bf(b.w);
        *(bf16x8*)(lbase + lane * 8) = v;
    }
}

// C[m][n] = (sum_k A[m][k]*B[n][k] + bias[n]) * scale   (BT-GEMM, m97 pattern)
// 1-D grid: bid = bz*(gridM*gridN) + bcol*gridM + brow; gridM % 8 == 0 so
// same-brow blocks (A-tile sharers) sit on one XCD.
template <typename AT, typename BT, typename OutT, bool HAS_BIAS>
__global__ __launch_bounds__(256) void gemm_bt(
    const AT* __restrict__ A,
    const BT* __restrict__ B,
    OutT* __restrict__ C,
    const float* __restrict__ bias,
    float scale, int K,
    long lda, long ldb, long ldc,
    long aBatch, long bBatch, long cBatch,
    int gridM, int gridN)
{
    __shared__ __align__(16) unsigned short As[BM * BK];
    __shared__ __align__(16) unsigned short Bs[BN * BK];

    const int tid  = threadIdx.x;
    const int wave = tid >> 6;
    const int lane = tid & 63;
    const int lr   = lane & 15;
    const int q4   = lane >> 4;
    const int wm   = wave >> 1;
    const int wn   = wave & 1;

    const int per  = gridM * gridN;
    const int bid  = blockIdx.x;
    const int bz   = bid / per;
    const int rem  = bid - bz * per;
    const int brow = rem % gridM;
    const int bcol = rem / gridM;

    const long m0 = (long)brow * BM;
    const long n0 = (long)bcol * BN;
    A += (long)bz * aBatch;
    B += (long)bz * bBatch;
    C += (long)bz * cBatch;

    const int srow  = lane >> 2;       // staging row within 16-row group
    const int skoff = (lane & 3) * 8;  // staging element offset in K

    f32x4 acc[4][4];
    const f32x4 zero = {0.f, 0.f, 0.f, 0.f};
#pragma unroll
    for (int i = 0; i < 4; i++)
#pragma unroll
        for (int j = 0; j < 4; j++) acc[i][j] = zero;

    const int nkt = K / BK;
    for (int kt = 0; kt < nkt; kt++) {
        const long k0 = (long)kt * BK;
        __syncthreads();
#pragma unroll
        for (int iss = 0; iss < 2; iss++) {
            const int rbase = wave * 32 + iss * 16;   // wave-uniform
            stage16(A + (m0 + rbase + srow) * lda + k0 + skoff, &As[rbase * BK], lane);
            stage16(B + (n0 + rbase + srow) * ldb + k0 + skoff, &Bs[rbase * BK], lane);
        }
        __syncthreads();

        bf16x8 af[4], bfr[4];
#pragma unroll
        for (int mi = 0; mi < 4; mi++)
            af[mi] = *(const bf16x8*)&As[(wm * 64 + mi * 16 + lr) * BK + q4 * 8];
#pragma unroll
        for (int ni = 0; ni < 4; ni++)
            bfr[ni] = *(const bf16x8*)&Bs[(wn * 64 + ni * 16 + lr) * BK + q4 * 8];
#pragma unroll
        for (int mi = 0; mi < 4; mi++)
#pragma unroll
            for (int ni = 0; ni < 4; ni++)
                acc[mi][ni] = __builtin_amdgcn_mfma_f32_16x16x32_bf16(
                    af[mi], bfr[ni], acc[mi][ni], 0, 0, 0);
    }

    // Verified C/D mapping: col = lane&15, row = quad*4 + reg.
#pragma unroll
    for (int ni = 0; ni < 4; ni++) {
        const long col = n0 + wn * 64 + ni * 16 + lr;
        const float bv = HAS_BIAS ? bias[col] : 0.f;
#pragma unroll
        for (int mi = 0; mi < 4; mi++) {
            const long row = m0 + wm * 64 + mi * 16 + q4 * 4;
#pragma unroll
            for (int r = 0; r < 4; r++) {
                float v = (acc[mi][ni][r] + bv) * scale;
                if constexpr (sizeof(OutT) == 2)
                    C[(row + r) * ldc + col] = (OutT)f2bf(v);
                else
                    C[(row + r) * ldc + col] = v;
            }
        }
    }
}

// Vproj[(s*16+n)*1024+f] bf16 -> Vt[n][f][s] bf16
__global__ __launch_bounds__(256) void transpose_v(
    const unsigned short* __restrict__ V, unsigned short* __restrict__ Vt)
{
    __shared__ unsigned short t[32][33];
    const int n = blockIdx.z;
    const int f0 = blockIdx.x * 32, s0 = blockIdx.y * 32;
    const int x = threadIdx.x;  // 0..31
#pragma unroll
    for (int i = threadIdx.y; i < 32; i += 8)
        t[i][x] = V[((long)(s0 + i) * 16 + n) * 1024 + f0 + x];
    __syncthreads();
#pragma unroll
    for (int i = threadIdx.y; i < 32; i += 8)
        Vt[(long)n * 1048576 + (long)(f0 + i) * 1024 + s0 + x] = t[x][i];
}

// In-place softmax on rows of 1024 bf16; f32 math; clamp keeps failures finite.
__global__ __launch_bounds__(256) void softmax_rows(unsigned short* __restrict__ base)
{
    unsigned short* p = base + (long)blockIdx.x * 1024;
    const int tid = threadIdx.x;
    ushort4 u = ((const ushort4*)p)[tid];
    float x0 = bf2f(u.x), x1 = bf2f(u.y), x2 = bf2f(u.z), x3 = bf2f(u.w);
    x0 = fminf(fmaxf(x0, -1e30f), 1e30f);
    x1 = fminf(fmaxf(x1, -1e30f), 1e30f);
    x2 = fminf(fmaxf(x2, -1e30f), 1e30f);
    x3 = fminf(fmaxf(x3, -1e30f), 1e30f);

    float m = fmaxf(fmaxf(x0, x1), fmaxf(x2, x3));
#pragma unroll
    for (int o = 32; o > 0; o >>= 1) m = fmaxf(m, __shfl_xor(m, o));
    __shared__ float redm[4], reds[4];
    const int wave = tid >> 6, lane = tid & 63;
    if (lane == 0) redm[wave] = m;
    __syncthreads();
    m = fmaxf(fmaxf(redm[0], redm[1]), fmaxf(redm[2], redm[3]));

    float e0 = __expf(x0 - m), e1 = __expf(x1 - m);
    float e2 = __expf(x2 - m), e3 = __expf(x3 - m);
    float s = e0 + e1 + e2 + e3;
#pragma unroll
    for (int o = 32; o > 0; o >>= 1) s += __shfl_xor(s, o);
    if (lane == 0) reds[wave] = s;
    __syncthreads();
    s = reds[0] + reds[1] + reds[2] + reds[3];
    const float inv = 1.0f / s;

    ushort4 ov = make_ushort4(f2bf(e0 * inv), f2bf(e1 * inv),
                              f2bf(e2 * inv), f2bf(e3 * inv));
    ((ushort4*)p)[tid] = ov;
}

extern "C" void kernel_launch(void* const* d_in, const int* in_sizes, int n_in,
                              void* d_out, int out_size, void* d_ws, size_t ws_size,
                              hipStream_t stream) {
    const float* query = (const float*)d_in[0];  // (1024,16,1024) f32
    const float* keyp  = (const float*)d_in[1];
    const float* valp  = (const float*)d_in[2];
    const float* wq    = (const float*)d_in[3];  // (1024,1024) f32
    const float* wk    = (const float*)d_in[4];
    const float* wv    = (const float*)d_in[5];
    const float* bias  = (const float*)d_in[6];  // (3072,) f32
    float* out = (float*)d_out;                  // 16777216 f32 = 64 MB

    unsigned short* W0 = (unsigned short*)d_ws;   // Vt[n][f][s], 32 MB
    unsigned short* W1 = W0 + 16777216;           // Vproj -> scores -> attn, 32 MB
    unsigned short* Qb = (unsigned short*)d_out;  // bytes [0,32MB), rows l*16+n
    unsigned short* Kb = Qb + 16777216;           // bytes [32,64MB), rows s*16+n

    const dim3 blk(256, 1, 1);
    const float qscale = 0.03125f;  // E^-0.5

    // 1. V projection (f32) -> W1 bf16, row = s*16+n   [gridM=128,gridN=8]
    gemm_bt<float, float, unsigned short, true><<<dim3(1024, 1, 1), blk, 0, stream>>>(
        valp, wv, W1, bias + 2048, 1.0f, 1024, 1024, 1024, 1024, 0, 0, 0, 128, 8);
    // 2. transpose -> W0 = Vt[n][f][s]; W1 now dead
    transpose_v<<<dim3(32, 32, 16), dim3(32, 8, 1), 0, stream>>>(W1, W0);
    // 3. Q projection -> Qb (d_out lower half), scaled by E^-0.5
    gemm_bt<float, float, unsigned short, true><<<dim3(1024, 1, 1), blk, 0, stream>>>(
        query, wq, Qb, bias, qscale, 1024, 1024, 1024, 1024, 0, 0, 0, 128, 8);
    // 4. K projection -> Kb (d_out upper half)
    gemm_bt<float, float, unsigned short, true><<<dim3(1024, 1, 1), blk, 0, stream>>>(
        keyp, wk, Kb, bias + 1024, 1.0f, 1024, 1024, 1024, 1024, 0, 0, 0, 128, 8);

    // 5. scores[n][l][s] bf16 -> W1 (overwrites dead Vproj) [gridM=8,gridN=8,16 batches]
    gemm_bt<unsigned short, unsigned short, unsigned short, false>
        <<<dim3(1024, 1, 1), blk, 0, stream>>>(
        Qb, Kb, W1, nullptr, 1.0f, 1024,
        16384, 16384, 1024, 1024, 1024, 1048576, 8, 8);

    // 6. softmax over s on all 16384 rows of W1 (in place)
    softmax_rows<<<dim3(16384, 1, 1), blk, 0, stream>>>(W1);

    // 7. out[(l*16+n)*1024+f] = attn_n[l][:] . Vt_n[f][:]
    //    Reads only W0/W1; overwrites ALL of d_out (Q/K staging dead).
    gemm_bt<unsigned short, unsigned short, float, false>
        <<<dim3(1024, 1, 1), blk, 0, stream>>>(
        W1, W0, out, nullptr, 1.0f, 1024,
        1024, 1024, 16384, 1048576, 1048576, 1024, 8, 8);
}